// Round 7
// baseline (142.498 us; speedup 1.0000x reference)
//
#include <hip/hip_runtime.h>

// Elman RNN, B=262144, IN=32, H=16, T=30, OUT=1, fp32 in/out.
// Round 7 (from round-6, 54 us dispatch). Issue accounting at 52% VALUBusy
// matched a model where the trans pipe is 8-lane (16 cyc per wave64 trans
// op): 8 trans/step = 128 of ~150 busy-cyc/step, ~48% of wall is bubbles.
//  - rcp -> bit-trick (0x7EF311C3) + 2 Newton iters: 4 trans ops/step move
//    off the scarce trans pipe onto the main VALU (64 -> 24 cyc). Preact
//    clamped to +-14 via v_med3 so exp2 can't overflow; tanh abs err
//    <= ~4e-4, below the fp16 state-rounding noise.
//  - TWO independent 16-row tiles per wave, source-interleaved. Round 4's
//    version of this failed because the compiler folded both chains into
//    32 VGPRs (serializing them); with the 5x lighter body two chains fit
//    in ~45 regs under the 64-reg cap of __launch_bounds__(256,8).
// Layout invariant (verified rounds 2-6): 16x16x16 MFMA B-frag layout ==
// C/D layout -> tanh(acc) repacks elementwise into the next B operand;
// state stays transposed (S = H^T), never crosses lanes.

#define T_STEPS 30
#define BLOCK   256
#define SCALE   2.8853900817779268f   // 2*log2(e)

typedef _Float16 v4h __attribute__((ext_vector_type(4)));
typedef __fp16   v2fp __attribute__((ext_vector_type(2)));
typedef float    v4f __attribute__((ext_vector_type(4)));

struct h4 { v2fp lo, hi; };

// tanh from pre-scaled preactivation a = 2*log2e*x.
// tanh = 1 - 2/(exp2(a)+1); rcp via magic-init + 2 Newton (VALU-only).
__device__ __forceinline__ float tanh_pre(float a) {
    float ac = __builtin_amdgcn_fmed3f(a, 14.0f, -14.0f);   // clamp [-14,14]
    float e  = __builtin_amdgcn_exp2f(ac);                  // 1 trans op
    float d  = 1.0f + e;                                    // d in [1, 16385]
    float r  = __uint_as_float(0x7EF311C3u - __float_as_uint(d)); // ~12% rel
    r = r * fmaf(-d, r, 2.0f);                              // Newton 1
    r = r * fmaf(-d, r, 2.0f);                              // Newton 2: ~2e-4
    return fmaf(-2.0f, r, 1.0f);
}

__global__ __launch_bounds__(BLOCK, 8) void rnn_mfma(
    const float* __restrict__ x,     // [B, 32]
    const float* __restrict__ W_ih,  // [16, 32]
    const float* __restrict__ W_hh,  // [16, 16]
    const float* __restrict__ b_ih,  // [16]
    const float* __restrict__ b_hh,  // [16]
    const float* __restrict__ W_fc,  // [1, 16]
    const float* __restrict__ b_fc,  // [1]
    float* __restrict__ out)         // [B, 30]
{
    __shared__ float tmp[128 * T_STEPS];  // 128 rows/block x 30 steps

    const int tid  = threadIdx.x;
    const int w    = tid >> 6;        // wave in block (0..3), 32 rows each
    const int lane = tid & 63;
    const int r    = lane & 15;       // MFMA row index
    const int q    = lane >> 4;       // quad
    const int j0   = 4 * q;

    const size_t rowA = (size_t)blockIdx.x * 128 + (size_t)w * 32 + r;
    const size_t rowB = rowA + 16;

    // ---- xproj for both tiles (exact fp32), C-fragment order:
    float a0 = b_ih[j0 + 0] + b_hh[j0 + 0];
    float a1 = b_ih[j0 + 1] + b_hh[j0 + 1];
    float a2 = b_ih[j0 + 2] + b_hh[j0 + 2];
    float a3 = b_ih[j0 + 3] + b_hh[j0 + 3];
    float c0 = a0, c1 = a1, c2 = a2, c3 = a3;
    {
        const float4* xA = (const float4*)(x + rowA * 32);
        const float4* xB = (const float4*)(x + rowB * 32);
#pragma unroll
        for (int c4 = 0; c4 < 8; ++c4) {
            float4 xa = xA[c4];
            float4 xb = xB[c4];
            const float4 w0 = *(const float4*)(W_ih + (j0 + 0) * 32 + c4 * 4);
            const float4 w1 = *(const float4*)(W_ih + (j0 + 1) * 32 + c4 * 4);
            const float4 w2 = *(const float4*)(W_ih + (j0 + 2) * 32 + c4 * 4);
            const float4 w3 = *(const float4*)(W_ih + (j0 + 3) * 32 + c4 * 4);
            a0 = fmaf(w0.x, xa.x, fmaf(w0.y, xa.y, fmaf(w0.z, xa.z, fmaf(w0.w, xa.w, a0))));
            a1 = fmaf(w1.x, xa.x, fmaf(w1.y, xa.y, fmaf(w1.z, xa.z, fmaf(w1.w, xa.w, a1))));
            a2 = fmaf(w2.x, xa.x, fmaf(w2.y, xa.y, fmaf(w2.z, xa.z, fmaf(w2.w, xa.w, a2))));
            a3 = fmaf(w3.x, xa.x, fmaf(w3.y, xa.y, fmaf(w3.z, xa.z, fmaf(w3.w, xa.w, a3))));
            c0 = fmaf(w0.x, xb.x, fmaf(w0.y, xb.y, fmaf(w0.z, xb.z, fmaf(w0.w, xb.w, c0))));
            c1 = fmaf(w1.x, xb.x, fmaf(w1.y, xb.y, fmaf(w1.z, xb.z, fmaf(w1.w, xb.w, c1))));
            c2 = fmaf(w2.x, xb.x, fmaf(w2.y, xb.y, fmaf(w2.z, xb.z, fmaf(w2.w, xb.w, c2))));
            c3 = fmaf(w3.x, xb.x, fmaf(w3.y, xb.y, fmaf(w3.z, xb.z, fmaf(w3.w, xb.w, c3))));
        }
    }
    // Pre-scaled by 2*log2e: tanh chain starts directly at med3/exp2.
    const v4f xpA = {a0 * SCALE, a1 * SCALE, a2 * SCALE, a3 * SCALE};
    const v4f xpB = {c0 * SCALE, c1 * SCALE, c2 * SCALE, c3 * SCALE};

    // ---- W_hh A-fragment in fp16 (RNE): A[m=r][k=4q+i] = SCALE*W_hh[r][4q+i]
    v4h whh;
    {
        float4 wr = *(const float4*)(W_hh + r * 16 + 4 * q);
        whh[0] = (_Float16)(wr.x * SCALE);
        whh[1] = (_Float16)(wr.y * SCALE);
        whh[2] = (_Float16)(wr.z * SCALE);
        whh[3] = (_Float16)(wr.w * SCALE);
    }

    // ---- fc A-fragment (UNSCALED): row0 = fp16(W_fc), row1 = fp16 residual
    v4h afc;
#pragma unroll
    for (int i = 0; i < 4; ++i) {
        float wv = W_fc[4 * q + i];
        _Float16 hi = (_Float16)wv;
        _Float16 lo = (_Float16)(wv - (float)hi);
        afc[i] = (r == 0) ? hi : ((r == 1) ? lo : (_Float16)0.0f);
    }
    const float bfc = b_fc[0];
    const v4f zfc = {(q == 0) ? bfc : 0.0f, 0.0f, 0.0f, 0.0f};

    // ---- two independent fp16 states (B-frag == C/D-frag layout)
    v4h sA = {(_Float16)0.0f, (_Float16)0.0f, (_Float16)0.0f, (_Float16)0.0f};
    v4h sB = sA;

    float* outA = &tmp[(w * 32 + r) * T_STEPS];   // lanes 0..15 write
    float* outB = outA + 16 * T_STEPS;

#pragma unroll
    for (int t = 0; t < T_STEPS; ++t) {
        // two MFMAs back-to-back: independent chains
        v4f accA = __builtin_amdgcn_mfma_f32_16x16x16f16(whh, sA, xpA, 0, 0, 0);
        v4f accB = __builtin_amdgcn_mfma_f32_16x16x16f16(whh, sB, xpB, 0, 0, 0);

        // interleaved tanh evaluation (scheduler can alternate chains)
        float hA0 = tanh_pre(accA[0]);
        float hB0 = tanh_pre(accB[0]);
        float hA1 = tanh_pre(accA[1]);
        float hB1 = tanh_pre(accB[1]);
        float hA2 = tanh_pre(accA[2]);
        float hB2 = tanh_pre(accB[2]);
        float hA3 = tanh_pre(accA[3]);
        float hB3 = tanh_pre(accB[3]);

        h4 pA, pB;
        pA.lo = __builtin_amdgcn_cvt_pkrtz(hA0, hA1);
        pA.hi = __builtin_amdgcn_cvt_pkrtz(hA2, hA3);
        pB.lo = __builtin_amdgcn_cvt_pkrtz(hB0, hB1);
        pB.hi = __builtin_amdgcn_cvt_pkrtz(hB2, hB3);
        sA = __builtin_bit_cast(v4h, pA);
        sB = __builtin_bit_cast(v4h, pB);

        // fc heads (leaves of the chains)
        v4f fA = __builtin_amdgcn_mfma_f32_16x16x16f16(afc, sA, zfc, 0, 0, 0);
        v4f fB = __builtin_amdgcn_mfma_f32_16x16x16f16(afc, sB, zfc, 0, 0, 0);

        if (lane < 16) {
            outA[t] = fA[0] + fA[1];
            outB[t] = fB[0] + fB[1];
        }
    }

    __syncthreads();

    // ---- coalesced writeout: block region out[block*128..+128)[0..30) contiguous
    float* oblk = out + (size_t)blockIdx.x * (128 * T_STEPS);
#pragma unroll
    for (int k = 0; k < (128 * T_STEPS) / BLOCK; ++k) {
        int idx = tid + k * BLOCK;
        oblk[idx] = tmp[idx];
    }
}

extern "C" void kernel_launch(void* const* d_in, const int* in_sizes, int n_in,
                              void* d_out, int out_size, void* d_ws, size_t ws_size,
                              hipStream_t stream) {
    // inputs: x, T, W_ih, W_hh, b_ih, b_hh, W_fc, b_fc
    const float* x    = (const float*)d_in[0];
    const float* W_ih = (const float*)d_in[2];
    const float* W_hh = (const float*)d_in[3];
    const float* b_ih = (const float*)d_in[4];
    const float* b_hh = (const float*)d_in[5];
    const float* W_fc = (const float*)d_in[6];
    const float* b_fc = (const float*)d_in[7];
    float* out = (float*)d_out;

    const int B = in_sizes[0] / 32;      // 262144
    const int grid = B / 128;            // 2048 blocks, 128 rows each

    rnn_mfma<<<grid, BLOCK, 0, stream>>>(x, W_ih, W_hh, b_ih, b_hh, W_fc, b_fc, out);
}

// Round 8
// 139.254 us; speedup vs baseline: 1.0233x; 1.0233x over previous
//
#include <hip/hip_runtime.h>

// Elman RNN, B=262144, IN=32, H=16, T=30, OUT=1, fp32 in/out.
// Round 8. Back to the R6 single-chain skeleton (54 us; dual-tile failed
// twice: compiler collapses both chains into 32 VGPRs and serializes).
// Issue model (validated R3/R6): trans op = 16 issue-cyc/wave64; R6 spends
// 128 of ~150 busy-cyc/step on 8 trans ops, wall 270 -> ~45% bubbles.
// Changes:
//  - Newton-rcp tanh: rcp -> magic 0x7EF311C3 + 2 Newton iters. Per tanh
//    8 VALU + 1 trans (32 cyc) vs 2 VALU + 2 trans (36 cyc); halves the
//    long-latency trans ops per step (8 -> 4), filling latency bubbles
//    with pipelined FMA work. Clamp preact to +-14 via v_med3 (domain
//    safety; tanh(4.85)=0.99987, clamp err 1.3e-4 < fp16 state noise).
//  - BLOCK 256 -> 128 (2 waves), grid 8192: finer per-CU packing, less
//    2-round quantization/drain (R6: 4096 blocks = exactly 2x8 blocks/CU).
// Layout invariant (verified R2-R7): 16x16x16 MFMA B-frag layout == C/D
// layout -> tanh(acc) repacks elementwise into the next B operand; state
// stays transposed (S = H^T), never crosses lanes.

#define T_STEPS 30
#define BLOCK   128
#define SCALE   2.8853900817779268f   // 2*log2(e)

typedef _Float16 v4h __attribute__((ext_vector_type(4)));
typedef __fp16   v2fp __attribute__((ext_vector_type(2)));
typedef float    v4f __attribute__((ext_vector_type(4)));

struct h4 { v2fp lo, hi; };

// tanh from pre-scaled preactivation a = 2*log2e*x.
// tanh = 1 - 2/(exp2(a)+1); reciprocal via magic-init + 2 Newton (VALU-only).
__device__ __forceinline__ float tanh_pre(float a) {
    float ac = __builtin_amdgcn_fmed3f(a, 14.0f, -14.0f);   // clamp [-14,14]
    float e  = __builtin_amdgcn_exp2f(ac);                  // only trans op
    float d  = 1.0f + e;                                    // d in (1, 16385]
    float r  = __uint_as_float(0x7EF311C3u - __float_as_uint(d)); // ~12% rel
    r = r * fmaf(-d, r, 2.0f);                              // Newton 1: ~1.5%
    r = r * fmaf(-d, r, 2.0f);                              // Newton 2: ~2e-4
    return fmaf(-2.0f, r, 1.0f);
}

__global__ __launch_bounds__(BLOCK, 8) void rnn_mfma(
    const float* __restrict__ x,     // [B, 32]
    const float* __restrict__ W_ih,  // [16, 32]
    const float* __restrict__ W_hh,  // [16, 16]
    const float* __restrict__ b_ih,  // [16]
    const float* __restrict__ b_hh,  // [16]
    const float* __restrict__ W_fc,  // [1, 16]
    const float* __restrict__ b_fc,  // [1]
    float* __restrict__ out)         // [B, 30]
{
    __shared__ float tmp[32 * T_STEPS];   // 32 rows/block x 30 steps

    const int tid  = threadIdx.x;
    const int w    = tid >> 6;        // wave in block (0..1), 16 rows each
    const int lane = tid & 63;
    const int r    = lane & 15;       // MFMA row index (batch row / A-row)
    const int q    = lane >> 4;       // quad
    const int j0   = 4 * q;

    const size_t row = (size_t)blockIdx.x * 32 + (size_t)w * 16 + r;

    // ---- xproj (exact fp32), C-fragment order: lane holds rows j=4q+i, col r.
    float a0 = b_ih[j0 + 0] + b_hh[j0 + 0];
    float a1 = b_ih[j0 + 1] + b_hh[j0 + 1];
    float a2 = b_ih[j0 + 2] + b_hh[j0 + 2];
    float a3 = b_ih[j0 + 3] + b_hh[j0 + 3];
    {
        const float4* xrow = (const float4*)(x + row * 32);
#pragma unroll
        for (int c4 = 0; c4 < 8; ++c4) {
            float4 xv = xrow[c4];
            const float4 w0 = *(const float4*)(W_ih + (j0 + 0) * 32 + c4 * 4);
            const float4 w1 = *(const float4*)(W_ih + (j0 + 1) * 32 + c4 * 4);
            const float4 w2 = *(const float4*)(W_ih + (j0 + 2) * 32 + c4 * 4);
            const float4 w3 = *(const float4*)(W_ih + (j0 + 3) * 32 + c4 * 4);
            a0 = fmaf(w0.x, xv.x, fmaf(w0.y, xv.y, fmaf(w0.z, xv.z, fmaf(w0.w, xv.w, a0))));
            a1 = fmaf(w1.x, xv.x, fmaf(w1.y, xv.y, fmaf(w1.z, xv.z, fmaf(w1.w, xv.w, a1))));
            a2 = fmaf(w2.x, xv.x, fmaf(w2.y, xv.y, fmaf(w2.z, xv.z, fmaf(w2.w, xv.w, a2))));
            a3 = fmaf(w3.x, xv.x, fmaf(w3.y, xv.y, fmaf(w3.z, xv.z, fmaf(w3.w, xv.w, a3))));
        }
    }
    // Pre-scaled by 2*log2e: tanh chain starts directly at med3/exp2.
    const v4f xpv = {a0 * SCALE, a1 * SCALE, a2 * SCALE, a3 * SCALE};

    // ---- W_hh A-fragment in fp16 (RNE): A[m=r][k=4q+i] = SCALE*W_hh[r][4q+i]
    v4h whh;
    {
        float4 wr = *(const float4*)(W_hh + r * 16 + 4 * q);
        whh[0] = (_Float16)(wr.x * SCALE);
        whh[1] = (_Float16)(wr.y * SCALE);
        whh[2] = (_Float16)(wr.z * SCALE);
        whh[3] = (_Float16)(wr.w * SCALE);
    }

    // ---- fc A-fragment (UNSCALED): row0 = fp16(W_fc), row1 = fp16 residual
    v4h afc;
#pragma unroll
    for (int i = 0; i < 4; ++i) {
        float wv = W_fc[4 * q + i];
        _Float16 hi = (_Float16)wv;
        _Float16 lo = (_Float16)(wv - (float)hi);
        afc[i] = (r == 0) ? hi : ((r == 1) ? lo : (_Float16)0.0f);
    }
    const float bfc = b_fc[0];
    const v4f zfc = {(q == 0) ? bfc : 0.0f, 0.0f, 0.0f, 0.0f};

    // ---- state S = H^T in fp16 (B-frag == C/D-frag layout)
    v4h s = {(_Float16)0.0f, (_Float16)0.0f, (_Float16)0.0f, (_Float16)0.0f};

    float* myout = &tmp[(w * 16 + r) * T_STEPS];   // lanes 0..15 write

#pragma unroll
    for (int t = 0; t < T_STEPS; ++t) {
        // preact (pre-scaled) = SCALE*Xp^T + (SCALE*W_hh)*S — one fp16 MFMA
        v4f acc = __builtin_amdgcn_mfma_f32_16x16x16f16(whh, s, xpv, 0, 0, 0);

        float h0 = tanh_pre(acc[0]);
        float h1 = tanh_pre(acc[1]);
        float h2 = tanh_pre(acc[2]);
        float h3 = tanh_pre(acc[3]);

        // repack state: 2 x v_cvt_pkrtz
        h4 p;
        p.lo = __builtin_amdgcn_cvt_pkrtz(h0, h1);
        p.hi = __builtin_amdgcn_cvt_pkrtz(h2, h3);
        s = __builtin_bit_cast(v4h, p);

        // fc head: one MFMA, rows 0(hi)+1(lo); leaf of the t-chain
        v4f f = __builtin_amdgcn_mfma_f32_16x16x16f16(afc, s, zfc, 0, 0, 0);

        if (lane < 16)
            myout[t] = f[0] + f[1];
    }

    __syncthreads();

    // ---- coalesced writeout: block region out[block*32..+32)[0..30) contiguous
    float* oblk = out + (size_t)blockIdx.x * (32 * T_STEPS);
    for (int idx = tid; idx < 32 * T_STEPS; idx += BLOCK)
        oblk[idx] = tmp[idx];
}

extern "C" void kernel_launch(void* const* d_in, const int* in_sizes, int n_in,
                              void* d_out, int out_size, void* d_ws, size_t ws_size,
                              hipStream_t stream) {
    // inputs: x, T, W_ih, W_hh, b_ih, b_hh, W_fc, b_fc
    const float* x    = (const float*)d_in[0];
    const float* W_ih = (const float*)d_in[2];
    const float* W_hh = (const float*)d_in[3];
    const float* b_ih = (const float*)d_in[4];
    const float* b_hh = (const float*)d_in[5];
    const float* W_fc = (const float*)d_in[6];
    const float* b_fc = (const float*)d_in[7];
    float* out = (float*)d_out;

    const int B = in_sizes[0] / 32;      // 262144
    const int grid = B / 32;             // 8192 blocks, 32 rows each

    rnn_mfma<<<grid, BLOCK, 0, stream>>>(x, W_ih, W_hh, b_ih, b_hh, W_fc, b_fc, out);
}